// Round 1
// baseline (688.977 us; speedup 1.0000x reference)
//
#include <hip/hip_runtime.h>
#include <cstdint>
#include <cstddef>

// ---------------------------------------------------------------------------
// HardInfoNCESyncLoss (B=8192, D=512):
//   loss = 0.5*(mean_i [lse(pos_i, top5 negs row i) - pos_i]
//             + mean_i [lse(pos_i, top5 negs col i) - pos_i]),  sim = v̂ â^T / 0.07
// Strategy: bf16 MFMA GEMM (never materialize sim), fused online top-5.
// ---------------------------------------------------------------------------

#define TSCALE (1.0f/0.07f)
#define NEG_INF (-__builtin_inff())

typedef __bf16 bf16_t;
typedef __bf16 bf16x8 __attribute__((ext_vector_type(8)));
typedef float  f32x4  __attribute__((ext_vector_type(4)));

// sorted-descending top5 insert
#define TRY5(v, A0,A1,A2,A3,A4) do { float _v=(v); \
  if (_v > A4) { \
    if (_v > A2) { \
      if (_v > A0)      { A4=A3; A3=A2; A2=A1; A1=A0; A0=_v; } \
      else if (_v > A1) { A4=A3; A3=A2; A2=A1; A1=_v; } \
      else              { A4=A3; A3=A2; A2=_v; } \
    } else { \
      if (_v > A3)      { A4=A3; A3=_v; } \
      else              { A4=_v; } \
    } \
  } } while(0)

static __device__ __forceinline__ void load_lds16(const void* g, void* l) {
  __builtin_amdgcn_global_load_lds(
      (const __attribute__((address_space(1))) void*)g,
      (__attribute__((address_space(3))) void*)(uint32_t)(uintptr_t)l,
      16, 0, 0);
}

// ---------------- kernel 1: L2-normalize, bf16 convert, exact pos ----------
__global__ __launch_bounds__(256)
void nrm_kernel(const float* __restrict__ v, const float* __restrict__ a,
                bf16_t* __restrict__ vb, bf16_t* __restrict__ ab,
                float* __restrict__ pos)
{
  int row  = blockIdx.x * 4 + (threadIdx.x >> 6);
  int lane = threadIdx.x & 63;
  size_t base = (size_t)row * 512 + (size_t)lane * 8;
  float4 v0 = *(const float4*)(v + base);
  float4 v1 = *(const float4*)(v + base + 4);
  float4 a0 = *(const float4*)(a + base);
  float4 a1 = *(const float4*)(a + base + 4);

  float sv = v0.x*v0.x+v0.y*v0.y+v0.z*v0.z+v0.w*v0.w
           + v1.x*v1.x+v1.y*v1.y+v1.z*v1.z+v1.w*v1.w;
  float sa = a0.x*a0.x+a0.y*a0.y+a0.z*a0.z+a0.w*a0.w
           + a1.x*a1.x+a1.y*a1.y+a1.z*a1.z+a1.w*a1.w;
  float sd = v0.x*a0.x+v0.y*a0.y+v0.z*a0.z+v0.w*a0.w
           + v1.x*a1.x+v1.y*a1.y+v1.z*a1.z+v1.w*a1.w;
  #pragma unroll
  for (int m = 32; m; m >>= 1) {
    sv += __shfl_xor(sv, m);
    sa += __shfl_xor(sa, m);
    sd += __shfl_xor(sd, m);
  }
  float iv = 1.0f / fmaxf(sqrtf(sv), 1e-12f);
  float ia = 1.0f / fmaxf(sqrtf(sa), 1e-12f);

  bf16x8 ov, oa;
  ov[0]=(bf16_t)(v0.x*iv); ov[1]=(bf16_t)(v0.y*iv); ov[2]=(bf16_t)(v0.z*iv); ov[3]=(bf16_t)(v0.w*iv);
  ov[4]=(bf16_t)(v1.x*iv); ov[5]=(bf16_t)(v1.y*iv); ov[6]=(bf16_t)(v1.z*iv); ov[7]=(bf16_t)(v1.w*iv);
  oa[0]=(bf16_t)(a0.x*ia); oa[1]=(bf16_t)(a0.y*ia); oa[2]=(bf16_t)(a0.z*ia); oa[3]=(bf16_t)(a0.w*ia);
  oa[4]=(bf16_t)(a1.x*ia); oa[5]=(bf16_t)(a1.y*ia); oa[6]=(bf16_t)(a1.z*ia); oa[7]=(bf16_t)(a1.w*ia);
  *(bf16x8*)(vb + base) = ov;
  *(bf16x8*)(ab + base) = oa;
  if (lane == 0) pos[row] = sd * iv * ia * TSCALE;   // pos pre-scaled by 1/T
}

// ---------------- kernel 2: GEMM (X Y^T) + fused per-row top5 --------------
// dir 0: X=vb,Y=ab -> rows of sim (v2a). dir 1: X=ab,Y=vb -> rows of sim^T.
// grid: [2 dirs][64 row-panels of 128][8 col-chunks of 1024]
#define KD 512
#define NCHUNK 8

__global__ __launch_bounds__(256, 2)
void gemm_topk(const bf16_t* __restrict__ vb, const bf16_t* __restrict__ ab,
               float* __restrict__ t5out)
{
  __shared__ __align__(16) char lds[65536];
  // buf0: A@0 (8K) B@8K  | buf1: A@16K B@24K | Ctile/merge @32K (32K)
  int tid  = threadIdx.x;
  int wave = tid >> 6;
  int lane = tid & 63;
  int wr = wave >> 1, wc = wave & 1;
  int r = lane & 15, q = lane >> 4;

  int bx    = blockIdx.x;
  int dir   = bx >> 9;
  int rem   = bx & 511;
  int panel = rem >> 3;
  int chunk = rem & 7;
  const bf16_t* X = dir ? ab : vb;
  const bf16_t* Y = dir ? vb : ab;
  int R0 = panel << 7;
  int C0 = chunk << 10;

  // private running top5: half A = rows R0+ (tid&63), half B = rows R0+64+(tid&63)
  float sA0=NEG_INF,sA1=NEG_INF,sA2=NEG_INF,sA3=NEG_INF,sA4=NEG_INF;
  float sB0=NEG_INF,sB1=NEG_INF,sB2=NEG_INF,sB3=NEG_INF,sB4=NEG_INF;

  for (int tile = 0; tile < NCHUNK; ++tile) {   // 8 tiles of 128 cols = 1024
    int tcol = C0 + (tile << 7);
    f32x4 acc[4][4];
    #pragma unroll
    for (int mi = 0; mi < 4; ++mi)
      #pragma unroll
      for (int ni = 0; ni < 4; ++ni)
        acc[mi][ni] = (f32x4){0.f,0.f,0.f,0.f};

    // stage K-step ks into buffer buf; LDS linear dest, inverse-swizzled source
    auto stage = [&](int k0, int buf) {
      #pragma unroll
      for (int call = 0; call < 2; ++call) {
        int p   = (call*4 + wave)*64 + lane;   // 16B chunk id, 0..511
        int row = p >> 2;
        int sl  = (p & 3) ^ (row & 3);         // involution swizzle
        const bf16_t* ga = X + (size_t)(R0   + row)*KD + k0 + sl*8;
        const bf16_t* gb = Y + (size_t)(tcol + row)*KD + k0 + sl*8;
        char* la = lds + buf*16384 +        (call*4 + wave)*1024;  // wave-uniform
        char* lb = lds + buf*16384 + 8192 + (call*4 + wave)*1024;
        load_lds16(ga, la);
        load_lds16(gb, lb);
      }
    };

    stage(0, 0);
    __syncthreads();
    for (int ks = 0; ks < 16; ++ks) {          // K = 512 = 16 * 32
      int cur = ks & 1;
      if (ks < 15) stage((ks+1)*32, cur ^ 1);
      const char* Ab = lds + cur*16384;
      const char* Bb = Ab + 8192;
      int ko = ((q ^ (r & 3)) << 4);           // swizzled k-slot byte offset
      bf16x8 af[4], bfr[4];
      #pragma unroll
      for (int mi = 0; mi < 4; ++mi)
        af[mi] = *(const bf16x8*)(Ab + (wr*64 + mi*16 + r)*64 + ko);
      #pragma unroll
      for (int ni = 0; ni < 4; ++ni)
        bfr[ni] = *(const bf16x8*)(Bb + (wc*64 + ni*16 + r)*64 + ko);
      #pragma unroll
      for (int mi = 0; mi < 4; ++mi)
        #pragma unroll
        for (int ni = 0; ni < 4; ++ni)
          acc[mi][ni] = __builtin_amdgcn_mfma_f32_16x16x32_bf16(af[mi], bfr[ni], acc[mi][ni], 0, 0, 0);
      __syncthreads();
    }

    // ---- epilogue: 2 halves of 64 rows through 32KB swizzled LDS tile ----
    bool hasDiag = (tcol == R0);

#define WRITE_FRAGS do { \
    _Pragma("unroll") \
    for (int mi_ = 0; mi_ < 4; ++mi_) { \
      _Pragma("unroll") \
      for (int ni_ = 0; ni_ < 4; ++ni_) { \
        int col_ = wc*64 + ni_*16 + r; \
        _Pragma("unroll") \
        for (int rg_ = 0; rg_ < 4; ++rg_) { \
          int rl_ = mi_*16 + q*4 + rg_; \
          int byte_ = ((rl_*128 + col_) << 2) ^ ((rl_ & 7) << 4); \
          *(float*)(lds + 32768 + byte_) = acc[mi_][ni_][rg_]; \
        } \
      } \
    } } while(0)

#define SCAN_HALF(A0,A1,A2,A3,A4, GROW) do { \
    int rl_ = tid & 63; int cp_ = tid >> 6; \
    int grow_ = (GROW); \
    _Pragma("unroll") \
    for (int j_ = 0; j_ < 8; ++j_) { \
      int cs_ = cp_*8 + j_; \
      f32x4 vv = *(const f32x4*)(lds + 32768 + rl_*512 + ((cs_ ^ (rl_ & 7)) << 4)); \
      if (hasDiag) { \
        int c0_ = tcol + cs_*4; \
        if (c0_   == grow_) vv[0] = NEG_INF; \
        if (c0_+1 == grow_) vv[1] = NEG_INF; \
        if (c0_+2 == grow_) vv[2] = NEG_INF; \
        if (c0_+3 == grow_) vv[3] = NEG_INF; \
      } \
      float mx_ = fmaxf(fmaxf(vv[0],vv[1]), fmaxf(vv[2],vv[3])); \
      if (mx_ > A4) { \
        TRY5(vv[0], A0,A1,A2,A3,A4); \
        TRY5(vv[1], A0,A1,A2,A3,A4); \
        TRY5(vv[2], A0,A1,A2,A3,A4); \
        TRY5(vv[3], A0,A1,A2,A3,A4); \
      } \
    } } while(0)

    if (wr == 0) WRITE_FRAGS;                 // rows 0..63
    __syncthreads();
    SCAN_HALF(sA0,sA1,sA2,sA3,sA4, R0 + (tid & 63));
    __syncthreads();
    if (wr == 1) WRITE_FRAGS;                 // rows 64..127
    __syncthreads();
    SCAN_HALF(sB0,sB1,sB2,sB3,sB4, R0 + 64 + (tid & 63));
    __syncthreads();
  }

  // ---- merge 4 copies per row, write chunk top5 to global ----
  float* t5 = (float*)(lds + 32768);          // [2][64][4][5] = 10KB
  {
    int rl = tid & 63, cp = tid >> 6;
    float* d0 = t5 + ((size_t)(rl)*4 + cp)*5;
    d0[0]=sA0; d0[1]=sA1; d0[2]=sA2; d0[3]=sA3; d0[4]=sA4;
    float* d1 = t5 + ((size_t)(64 + rl)*4 + cp)*5;
    d1[0]=sB0; d1[1]=sB1; d1[2]=sB2; d1[3]=sB3; d1[4]=sB4;
  }
  __syncthreads();
  if (tid < 128) {
    int h = tid >> 6, rr = tid & 63;
    const float* s = t5 + ((size_t)(h*64 + rr)*4)*5;
    float m0=NEG_INF,m1=NEG_INF,m2=NEG_INF,m3=NEG_INF,m4=NEG_INF;
    #pragma unroll
    for (int j = 0; j < 20; ++j) TRY5(s[j], m0,m1,m2,m3,m4);
    int grow = R0 + h*64 + rr;
    float* dst = t5out + (((size_t)dir*8192 + grow)*NCHUNK + chunk)*5;
    dst[0]=m0; dst[1]=m1; dst[2]=m2; dst[3]=m3; dst[4]=m4;
  }
}

// ---------------- kernel 3: per-row merge + logsumexp ----------------------
__global__ __launch_bounds__(256)
void merge_kernel(const float* __restrict__ t5, const float* __restrict__ pos,
                  float* __restrict__ partials)
{
  int i = blockIdx.x*256 + threadIdx.x;
  float p = pos[i];                            // already scaled by 1/T
  float total = 0.f;
  #pragma unroll
  for (int dir = 0; dir < 2; ++dir) {
    const float* s = t5 + ((size_t)dir*8192 + i)*NCHUNK*5;
    float a0=NEG_INF,a1=NEG_INF,a2=NEG_INF,a3=NEG_INF,a4=NEG_INF;
    for (int j = 0; j < NCHUNK*5; ++j) TRY5(s[j], a0,a1,a2,a3,a4);
    float m = fmaxf(p, a0*TSCALE);
    float sum = expf(p - m)
              + expf(a0*TSCALE - m) + expf(a1*TSCALE - m) + expf(a2*TSCALE - m)
              + expf(a3*TSCALE - m) + expf(a4*TSCALE - m);
    total += m + logf(sum) - p;
  }
  #pragma unroll
  for (int m = 32; m; m >>= 1) total += __shfl_xor(total, m);
  __shared__ float wsum[4];
  if ((threadIdx.x & 63) == 0) wsum[threadIdx.x >> 6] = total;
  __syncthreads();
  if (threadIdx.x == 0)
    partials[blockIdx.x] = wsum[0]+wsum[1]+wsum[2]+wsum[3];
}

// ---------------- kernel 4: final scalar -----------------------------------
__global__ void final_kernel(const float* __restrict__ partials, float* __restrict__ out)
{
  int lane = threadIdx.x;
  float v = (lane < 32) ? partials[lane] : 0.f;
  #pragma unroll
  for (int m = 32; m; m >>= 1) v += __shfl_xor(v, m);
  if (lane == 0) out[0] = 0.5f * v / 8192.0f;
}

// ---------------------------------------------------------------------------
extern "C" void kernel_launch(void* const* d_in, const int* in_sizes, int n_in,
                              void* d_out, int out_size, void* d_ws, size_t ws_size,
                              hipStream_t stream)
{
  const float* v = (const float*)d_in[0];
  const float* a = (const float*)d_in[1];
  char* ws = (char*)d_ws;

  constexpr size_t OFF_AB   = 8ull*1024*1024;
  constexpr size_t OFF_POS  = 16ull*1024*1024;
  constexpr size_t OFF_T5   = OFF_POS + 32*1024;
  constexpr size_t T5_BYTES = 2ull*8192*NCHUNK*5*4;   // 2,621,440
  constexpr size_t OFF_PART = OFF_T5 + T5_BYTES;

  bf16_t* vb  = (bf16_t*)ws;
  bf16_t* ab  = (bf16_t*)(ws + OFF_AB);
  float* pos  = (float*)(ws + OFF_POS);
  float* t5   = (float*)(ws + OFF_T5);
  float* part = (float*)(ws + OFF_PART);
  float* out  = (float*)d_out;

  hipLaunchKernelGGL(nrm_kernel,   dim3(2048), dim3(256), 0, stream, v, a, vb, ab, pos);
  hipLaunchKernelGGL(gemm_topk,    dim3(1024), dim3(256), 0, stream, vb, ab, t5);
  hipLaunchKernelGGL(merge_kernel, dim3(32),   dim3(256), 0, stream, t5, pos, part);
  hipLaunchKernelGGL(final_kernel, dim3(1),    dim3(64),  0, stream, part, out);
}

// Round 2
// 682.257 us; speedup vs baseline: 1.0098x; 1.0098x over previous
//
#include <hip/hip_runtime.h>
#include <cstdint>
#include <cstddef>

// ---------------------------------------------------------------------------
// HardInfoNCESyncLoss (B=8192, D=512):
//   loss = 0.5*(mean_i [lse(pos_i, top5 row-negs i) + mean_i lse(pos_i, top5 col-negs i)] - pos terms)
// Round 2: ONE GEMM pass feeds both directions (row scan = v2a, col scan = a2v),
// LDS cut 64KB->32KB (epilogue reuses staging buffers) for 4 blocks/CU.
// ---------------------------------------------------------------------------

#define TSCALE (1.0f/0.07f)
#define NEG_INF (-__builtin_inff())
#define KD 512
#define NCHUNK 8

typedef __bf16 bf16_t;
typedef __bf16 bf16x8 __attribute__((ext_vector_type(8)));
typedef float  f32x4  __attribute__((ext_vector_type(4)));

// sorted-descending top5 insert
#define TRY5(v, A0,A1,A2,A3,A4) do { float _v=(v); \
  if (_v > A4) { \
    if (_v > A2) { \
      if (_v > A0)      { A4=A3; A3=A2; A2=A1; A1=A0; A0=_v; } \
      else if (_v > A1) { A4=A3; A3=A2; A2=A1; A1=_v; } \
      else              { A4=A3; A3=A2; A2=_v; } \
    } else { \
      if (_v > A3)      { A4=A3; A3=_v; } \
      else              { A4=_v; } \
    } \
  } } while(0)

static __device__ __forceinline__ void load_lds16(const void* g, void* l) {
  __builtin_amdgcn_global_load_lds(
      (const __attribute__((address_space(1))) void*)g,
      (__attribute__((address_space(3))) void*)(uint32_t)(uintptr_t)l,
      16, 0, 0);
}

// ---------------- kernel 1: L2-normalize, bf16 convert, exact pos ----------
__global__ __launch_bounds__(256)
void nrm_kernel(const float* __restrict__ v, const float* __restrict__ a,
                bf16_t* __restrict__ vb, bf16_t* __restrict__ ab,
                float* __restrict__ pos)
{
  int row  = blockIdx.x * 4 + (threadIdx.x >> 6);
  int lane = threadIdx.x & 63;
  size_t base = (size_t)row * 512 + (size_t)lane * 8;
  float4 v0 = *(const float4*)(v + base);
  float4 v1 = *(const float4*)(v + base + 4);
  float4 a0 = *(const float4*)(a + base);
  float4 a1 = *(const float4*)(a + base + 4);

  float sv = v0.x*v0.x+v0.y*v0.y+v0.z*v0.z+v0.w*v0.w
           + v1.x*v1.x+v1.y*v1.y+v1.z*v1.z+v1.w*v1.w;
  float sa = a0.x*a0.x+a0.y*a0.y+a0.z*a0.z+a0.w*a0.w
           + a1.x*a1.x+a1.y*a1.y+a1.z*a1.z+a1.w*a1.w;
  float sd = v0.x*a0.x+v0.y*a0.y+v0.z*a0.z+v0.w*a0.w
           + v1.x*a1.x+v1.y*a1.y+v1.z*a1.z+v1.w*a1.w;
  #pragma unroll
  for (int m = 32; m; m >>= 1) {
    sv += __shfl_xor(sv, m);
    sa += __shfl_xor(sa, m);
    sd += __shfl_xor(sd, m);
  }
  float iv = 1.0f / fmaxf(sqrtf(sv), 1e-12f);
  float ia = 1.0f / fmaxf(sqrtf(sa), 1e-12f);

  bf16x8 ov, oa;
  ov[0]=(bf16_t)(v0.x*iv); ov[1]=(bf16_t)(v0.y*iv); ov[2]=(bf16_t)(v0.z*iv); ov[3]=(bf16_t)(v0.w*iv);
  ov[4]=(bf16_t)(v1.x*iv); ov[5]=(bf16_t)(v1.y*iv); ov[6]=(bf16_t)(v1.z*iv); ov[7]=(bf16_t)(v1.w*iv);
  oa[0]=(bf16_t)(a0.x*ia); oa[1]=(bf16_t)(a0.y*ia); oa[2]=(bf16_t)(a0.z*ia); oa[3]=(bf16_t)(a0.w*ia);
  oa[4]=(bf16_t)(a1.x*ia); oa[5]=(bf16_t)(a1.y*ia); oa[6]=(bf16_t)(a1.z*ia); oa[7]=(bf16_t)(a1.w*ia);
  *(bf16x8*)(vb + base) = ov;
  *(bf16x8*)(ab + base) = oa;
  if (lane == 0) pos[row] = sd * iv * ia * TSCALE;   // pos pre-scaled by 1/T
}

// ---------------- kernel 2: GEMM tile + fused row-top5 AND col-top5 --------
// grid: [64 row-panels of 128][8 col-chunks of 1024]  (512 blocks, ONE pass)
__global__ __launch_bounds__(256, 4)
void gemm_topk(const bf16_t* __restrict__ vb, const bf16_t* __restrict__ ab,
               float* __restrict__ t5v, float* __restrict__ t5a)
{
  __shared__ __align__(16) char lds[32768];
  // staging: buf0 @0 (A 8K, B 8K), buf1 @16K. Epilogue reuses [0,32K).
  int tid  = threadIdx.x;
  int wave = tid >> 6;
  int lane = tid & 63;
  int wr = wave >> 1, wc = wave & 1;
  int r = lane & 15, q = lane >> 4;

  int panel = blockIdx.x >> 3;
  int chunk = blockIdx.x & 7;
  int R0 = panel << 7;
  int C0 = chunk << 10;

  // running row-top5: half A = row R0+(tid&63), half B = row R0+64+(tid&63),
  // copy (tid>>6) covers col-subset per tile; merged at block end.
  float sA0=NEG_INF,sA1=NEG_INF,sA2=NEG_INF,sA3=NEG_INF,sA4=NEG_INF;
  float sB0=NEG_INF,sB1=NEG_INF,sB2=NEG_INF,sB3=NEG_INF,sB4=NEG_INF;

  for (int tile = 0; tile < NCHUNK; ++tile) {   // 8 tiles of 128 cols
    int tcol = C0 + (tile << 7);
    f32x4 acc[4][4];
    #pragma unroll
    for (int mi = 0; mi < 4; ++mi)
      #pragma unroll
      for (int ni = 0; ni < 4; ++ni)
        acc[mi][ni] = (f32x4){0.f,0.f,0.f,0.f};

    auto stage = [&](int k0, int buf) {
      #pragma unroll
      for (int call = 0; call < 2; ++call) {
        int p   = (call*4 + wave)*64 + lane;   // 16B chunk id
        int row = p >> 2;
        int sl  = (p & 3) ^ (row & 3);         // involution swizzle on source
        const bf16_t* ga = vb + (size_t)(R0   + row)*KD + k0 + sl*8;
        const bf16_t* gb = ab + (size_t)(tcol + row)*KD + k0 + sl*8;
        char* la = lds + buf*16384 +        (call*4 + wave)*1024;  // wave-uniform
        char* lb = lds + buf*16384 + 8192 + (call*4 + wave)*1024;
        load_lds16(ga, la);
        load_lds16(gb, lb);
      }
    };

    stage(0, 0);
    __syncthreads();
    for (int ks = 0; ks < 16; ++ks) {          // K = 512 = 16 * 32
      int cur = ks & 1;
      if (ks < 15) stage((ks+1)*32, cur ^ 1);
      const char* Ab = lds + cur*16384;
      const char* Bb = Ab + 8192;
      int ko = ((q ^ (r & 3)) << 4);           // swizzled k-slot byte offset
      bf16x8 af[4], bfr[4];
      #pragma unroll
      for (int mi = 0; mi < 4; ++mi)
        af[mi] = *(const bf16x8*)(Ab + (wr*64 + mi*16 + r)*64 + ko);
      #pragma unroll
      for (int ni = 0; ni < 4; ++ni)
        bfr[ni] = *(const bf16x8*)(Bb + (wc*64 + ni*16 + r)*64 + ko);
      #pragma unroll
      for (int mi = 0; mi < 4; ++mi)
        #pragma unroll
        for (int ni = 0; ni < 4; ++ni)
          acc[mi][ni] = __builtin_amdgcn_mfma_f32_16x16x32_bf16(af[mi], bfr[ni], acc[mi][ni], 0, 0, 0);
      __syncthreads();
    }

    // ---- diag mask once, in registers (serves both scans) ----
    // global row = R0 + wr*64 + mi*16 + q*4 + rg ; global col = tcol + wc*64 + ni*16 + r
    if (tcol == R0 && wr == wc && (r >> 2) == q) {
      #pragma unroll
      for (int mi = 0; mi < 4; ++mi)
        acc[mi][mi][r & 3] = NEG_INF;
    }

    // ---- column top5 (a2v): per-thread register reduce, LDS merge ----
    {
      float c5[4][5];
      #pragma unroll
      for (int ni = 0; ni < 4; ++ni) {
        #pragma unroll
        for (int z = 0; z < 5; ++z) c5[ni][z] = NEG_INF;
        #pragma unroll
        for (int mi = 0; mi < 4; ++mi)
          #pragma unroll
          for (int rg = 0; rg < 4; ++rg)
            TRY5(acc[mi][ni][rg], c5[ni][0],c5[ni][1],c5[ni][2],c5[ni][3],c5[ni][4]);
      }
      float* cm = (float*)lds;                 // [128 cols][8 copies][5]
      int cp2 = wr*4 + q;
      #pragma unroll
      for (int ni = 0; ni < 4; ++ni) {
        int cl = wc*64 + ni*16 + r;
        float* d = cm + ((size_t)cl*8 + cp2)*5;
        #pragma unroll
        for (int z = 0; z < 5; ++z) d[z] = c5[ni][z];
      }
      __syncthreads();
      if (tid < 128) {
        const float* s = cm + (size_t)tid*40;
        float m0=NEG_INF,m1=NEG_INF,m2=NEG_INF,m3=NEG_INF,m4=NEG_INF;
        #pragma unroll
        for (int j = 0; j < 40; ++j) TRY5(s[j], m0,m1,m2,m3,m4);
        float* dst = t5a + ((size_t)(tcol + tid)*64 + panel)*5;
        dst[0]=m0; dst[1]=m1; dst[2]=m2; dst[3]=m3; dst[4]=m4;
      }
      __syncthreads();
    }

    // ---- row top5 (v2a): C-halves through 32KB swizzled LDS tile ----
#define WRITE_FRAGS do { \
    _Pragma("unroll") \
    for (int mi_ = 0; mi_ < 4; ++mi_) { \
      _Pragma("unroll") \
      for (int ni_ = 0; ni_ < 4; ++ni_) { \
        int col_ = wc*64 + ni_*16 + r; \
        _Pragma("unroll") \
        for (int rg_ = 0; rg_ < 4; ++rg_) { \
          int rl_ = mi_*16 + q*4 + rg_; \
          int byte_ = ((rl_*128 + col_) << 2) ^ ((rl_ & 7) << 4); \
          *(float*)(lds + byte_) = acc[mi_][ni_][rg_]; \
        } \
      } \
    } } while(0)

#define SCAN_HALF(A0,A1,A2,A3,A4) do { \
    int rl_ = tid & 63; int cp_ = tid >> 6; \
    _Pragma("unroll") \
    for (int j_ = 0; j_ < 8; ++j_) { \
      int cs_ = cp_*8 + j_; \
      f32x4 vv = *(const f32x4*)(lds + rl_*512 + ((cs_ ^ (rl_ & 7)) << 4)); \
      float mx_ = fmaxf(fmaxf(vv[0],vv[1]), fmaxf(vv[2],vv[3])); \
      if (mx_ > A4) { \
        TRY5(vv[0], A0,A1,A2,A3,A4); \
        TRY5(vv[1], A0,A1,A2,A3,A4); \
        TRY5(vv[2], A0,A1,A2,A3,A4); \
        TRY5(vv[3], A0,A1,A2,A3,A4); \
      } \
    } } while(0)

    if (wr == 0) WRITE_FRAGS;                 // rows 0..63
    __syncthreads();
    SCAN_HALF(sA0,sA1,sA2,sA3,sA4);
    __syncthreads();
    if (wr == 1) WRITE_FRAGS;                 // rows 64..127
    __syncthreads();
    SCAN_HALF(sB0,sB1,sB2,sB3,sB4);
    __syncthreads();
  }

  // ---- merge 4 col-subset copies per row, write chunk top5 ----
  float* t5m = (float*)lds;                   // [128][4][5] = 10KB
  {
    int rl = tid & 63, cp = tid >> 6;
    float* d0 = t5m + ((size_t)rl*4 + cp)*5;
    d0[0]=sA0; d0[1]=sA1; d0[2]=sA2; d0[3]=sA3; d0[4]=sA4;
    float* d1 = t5m + ((size_t)(64 + rl)*4 + cp)*5;
    d1[0]=sB0; d1[1]=sB1; d1[2]=sB2; d1[3]=sB3; d1[4]=sB4;
  }
  __syncthreads();
  if (tid < 128) {
    int h = tid >> 6, rr = tid & 63;
    const float* s = t5m + ((size_t)(h*64 + rr)*4)*5;
    float m0=NEG_INF,m1=NEG_INF,m2=NEG_INF,m3=NEG_INF,m4=NEG_INF;
    #pragma unroll
    for (int j = 0; j < 20; ++j) TRY5(s[j], m0,m1,m2,m3,m4);
    int grow = R0 + h*64 + rr;
    float* dst = t5v + ((size_t)grow*NCHUNK + chunk)*5;
    dst[0]=m0; dst[1]=m1; dst[2]=m2; dst[3]=m3; dst[4]=m4;
  }
}

// ---------------- kernel 3: per-row merge + logsumexp ----------------------
__global__ __launch_bounds__(256)
void merge_kernel(const float* __restrict__ t5v, const float* __restrict__ t5a,
                  const float* __restrict__ pos, float* __restrict__ partials)
{
  int i = blockIdx.x*256 + threadIdx.x;
  float p = pos[i];                            // already scaled by 1/T
  float total = 0.f;
  {
    const float* s = t5v + (size_t)i*NCHUNK*5;
    float a0=NEG_INF,a1=NEG_INF,a2=NEG_INF,a3=NEG_INF,a4=NEG_INF;
    for (int j = 0; j < NCHUNK*5; ++j) TRY5(s[j], a0,a1,a2,a3,a4);
    float m = fmaxf(p, a0*TSCALE);
    float sum = expf(p - m)
              + expf(a0*TSCALE - m) + expf(a1*TSCALE - m) + expf(a2*TSCALE - m)
              + expf(a3*TSCALE - m) + expf(a4*TSCALE - m);
    total += m + logf(sum) - p;
  }
  {
    const float* s = t5a + (size_t)i*64*5;
    float a0=NEG_INF,a1=NEG_INF,a2=NEG_INF,a3=NEG_INF,a4=NEG_INF;
    for (int j = 0; j < 64*5; ++j) TRY5(s[j], a0,a1,a2,a3,a4);
    float m = fmaxf(p, a0*TSCALE);
    float sum = expf(p - m)
              + expf(a0*TSCALE - m) + expf(a1*TSCALE - m) + expf(a2*TSCALE - m)
              + expf(a3*TSCALE - m) + expf(a4*TSCALE - m);
    total += m + logf(sum) - p;
  }
  #pragma unroll
  for (int m = 32; m; m >>= 1) total += __shfl_xor(total, m);
  __shared__ float wsum[4];
  if ((threadIdx.x & 63) == 0) wsum[threadIdx.x >> 6] = total;
  __syncthreads();
  if (threadIdx.x == 0)
    partials[blockIdx.x] = wsum[0]+wsum[1]+wsum[2]+wsum[3];
}

// ---------------- kernel 4: final scalar -----------------------------------
__global__ void final_kernel(const float* __restrict__ partials, float* __restrict__ out)
{
  int lane = threadIdx.x;
  float v = (lane < 32) ? partials[lane] : 0.f;
  #pragma unroll
  for (int m = 32; m; m >>= 1) v += __shfl_xor(v, m);
  if (lane == 0) out[0] = 0.5f * v / 8192.0f;
}

// ---------------------------------------------------------------------------
extern "C" void kernel_launch(void* const* d_in, const int* in_sizes, int n_in,
                              void* d_out, int out_size, void* d_ws, size_t ws_size,
                              hipStream_t stream)
{
  const float* v = (const float*)d_in[0];
  const float* a = (const float*)d_in[1];
  char* ws = (char*)d_ws;

  constexpr size_t OFF_AB   = 8ull*1024*1024;
  constexpr size_t OFF_POS  = 16ull*1024*1024;
  constexpr size_t OFF_T5V  = OFF_POS + 64*1024;
  constexpr size_t T5V_B    = 8192ull*NCHUNK*5*4;      // 1.25 MB
  constexpr size_t OFF_T5A  = OFF_T5V + 2ull*1024*1024;
  constexpr size_t T5A_B    = 8192ull*64*5*4;          // 10 MB
  constexpr size_t OFF_PART = OFF_T5A + T5A_B + 1024;

  bf16_t* vb  = (bf16_t*)ws;
  bf16_t* ab  = (bf16_t*)(ws + OFF_AB);
  float* pos  = (float*)(ws + OFF_POS);
  float* t5v  = (float*)(ws + OFF_T5V);
  float* t5a  = (float*)(ws + OFF_T5A);
  float* part = (float*)(ws + OFF_PART);
  float* out  = (float*)d_out;

  hipLaunchKernelGGL(nrm_kernel,   dim3(2048), dim3(256), 0, stream, v, a, vb, ab, pos);
  hipLaunchKernelGGL(gemm_topk,    dim3(512),  dim3(256), 0, stream, vb, ab, t5v, t5a);
  hipLaunchKernelGGL(merge_kernel, dim3(32),   dim3(256), 0, stream, t5v, t5a, pos, part);
  hipLaunchKernelGGL(final_kernel, dim3(1),    dim3(64),  0, stream, part, out);
}

// Round 3
// 651.277 us; speedup vs baseline: 1.0579x; 1.0476x over previous
//
#include <hip/hip_runtime.h>
#include <cstdint>
#include <cstddef>

// ---------------------------------------------------------------------------
// HardInfoNCESyncLoss (B=8192, D=512)  — round 3
// One GEMM pass feeds both directions. K-loop rebuilt as counted-vmcnt
// pipeline (T3/T4): 3 LDS buffers, depth-2 prefetch, raw s_barrier,
// s_waitcnt vmcnt(8) steady-state (never 0 mid-loop). Grid 1024, 3 blk/CU.
// ---------------------------------------------------------------------------

#define TSCALE (1.0f/0.07f)
#define NEG_INF (-__builtin_inff())
#define KD 512

typedef __bf16 bf16_t;
typedef __bf16 bf16x8 __attribute__((ext_vector_type(8)));
typedef float  f32x4  __attribute__((ext_vector_type(4)));

#define TRY5(v, A0,A1,A2,A3,A4) do { float _v=(v); \
  if (_v > A4) { \
    if (_v > A2) { \
      if (_v > A0)      { A4=A3; A3=A2; A2=A1; A1=A0; A0=_v; } \
      else if (_v > A1) { A4=A3; A3=A2; A2=A1; A1=_v; } \
      else              { A4=A3; A3=A2; A2=_v; } \
    } else { \
      if (_v > A3)      { A4=A3; A3=_v; } \
      else              { A4=_v; } \
    } \
  } } while(0)

#define VMW8()  asm volatile("s_waitcnt vmcnt(8)"  ::: "memory")
#define VMW4()  asm volatile("s_waitcnt vmcnt(4)"  ::: "memory")
#define VMW0()  asm volatile("s_waitcnt vmcnt(0)"  ::: "memory")
#define LGKM0() asm volatile("s_waitcnt lgkmcnt(0)" ::: "memory")
#define SBAR()  __builtin_amdgcn_s_barrier()
#define SCHED0() __builtin_amdgcn_sched_barrier(0)

static __device__ __forceinline__ void load_lds16(const void* g, void* l) {
  __builtin_amdgcn_global_load_lds(
      (const __attribute__((address_space(1))) void*)g,
      (__attribute__((address_space(3))) void*)(uint32_t)(uintptr_t)l,
      16, 0, 0);
}

// ---------------- kernel 1: L2-normalize, bf16 convert, exact pos ----------
__global__ __launch_bounds__(256)
void nrm_kernel(const float* __restrict__ v, const float* __restrict__ a,
                bf16_t* __restrict__ vb, bf16_t* __restrict__ ab,
                float* __restrict__ pos)
{
  int row  = blockIdx.x * 4 + (threadIdx.x >> 6);
  int lane = threadIdx.x & 63;
  size_t base = (size_t)row * 512 + (size_t)lane * 8;
  float4 v0 = *(const float4*)(v + base);
  float4 v1 = *(const float4*)(v + base + 4);
  float4 a0 = *(const float4*)(a + base);
  float4 a1 = *(const float4*)(a + base + 4);

  float sv = v0.x*v0.x+v0.y*v0.y+v0.z*v0.z+v0.w*v0.w
           + v1.x*v1.x+v1.y*v1.y+v1.z*v1.z+v1.w*v1.w;
  float sa = a0.x*a0.x+a0.y*a0.y+a0.z*a0.z+a0.w*a0.w
           + a1.x*a1.x+a1.y*a1.y+a1.z*a1.z+a1.w*a1.w;
  float sd = v0.x*a0.x+v0.y*a0.y+v0.z*a0.z+v0.w*a0.w
           + v1.x*a1.x+v1.y*a1.y+v1.z*a1.z+v1.w*a1.w;
  #pragma unroll
  for (int m = 32; m; m >>= 1) {
    sv += __shfl_xor(sv, m);
    sa += __shfl_xor(sa, m);
    sd += __shfl_xor(sd, m);
  }
  float iv = 1.0f / fmaxf(sqrtf(sv), 1e-12f);
  float ia = 1.0f / fmaxf(sqrtf(sa), 1e-12f);

  bf16x8 ov, oa;
  ov[0]=(bf16_t)(v0.x*iv); ov[1]=(bf16_t)(v0.y*iv); ov[2]=(bf16_t)(v0.z*iv); ov[3]=(bf16_t)(v0.w*iv);
  ov[4]=(bf16_t)(v1.x*iv); ov[5]=(bf16_t)(v1.y*iv); ov[6]=(bf16_t)(v1.z*iv); ov[7]=(bf16_t)(v1.w*iv);
  oa[0]=(bf16_t)(a0.x*ia); oa[1]=(bf16_t)(a0.y*ia); oa[2]=(bf16_t)(a0.z*ia); oa[3]=(bf16_t)(a0.w*ia);
  oa[4]=(bf16_t)(a1.x*ia); oa[5]=(bf16_t)(a1.y*ia); oa[6]=(bf16_t)(a1.z*ia); oa[7]=(bf16_t)(a1.w*ia);
  *(bf16x8*)(vb + base) = ov;
  *(bf16x8*)(ab + base) = oa;
  if (lane == 0) pos[row] = sd * iv * ia * TSCALE;
}

// ---------------- kernel 2: pipelined GEMM + fused row/col top5 ------------
// grid 1024: xcd = bx&7; idx = bx>>3; chunk = xcd | ((idx&1)<<3)  (16 chunks
// of 512 cols, pinned per-XCD so B stays L2-resident); panel = idx>>1 (64
// panels of 128 rows). 4 tiles of 128 cols per block.
__global__ __launch_bounds__(256, 3)
void gemm_topk(const bf16_t* __restrict__ vb, const bf16_t* __restrict__ ab,
               float* __restrict__ t5v, float* __restrict__ t5a)
{
  __shared__ __align__(16) char lds[49152];   // 3 x (A 8K + B 8K)
  int tid  = threadIdx.x;
  int wave = tid >> 6;
  int lane = tid & 63;
  int wr = wave >> 1, wc = wave & 1;
  int r = lane & 15, q = lane >> 4;

  int bx    = blockIdx.x;
  int xcd   = bx & 7;
  int idx   = bx >> 3;
  int chunk = xcd | ((idx & 1) << 3);
  int panel = idx >> 1;
  int R0 = panel << 7;
  int C0 = chunk << 9;                        // 512-col chunk

  float sA0=NEG_INF,sA1=NEG_INF,sA2=NEG_INF,sA3=NEG_INF,sA4=NEG_INF;
  float sB0=NEG_INF,sB1=NEG_INF,sB2=NEG_INF,sB3=NEG_INF,sB4=NEG_INF;

  for (int tile = 0; tile < 4; ++tile) {      // 4 tiles of 128 cols
    int tcol = C0 + (tile << 7);
    f32x4 acc[4][4];
    #pragma unroll
    for (int mi = 0; mi < 4; ++mi)
      #pragma unroll
      for (int ni = 0; ni < 4; ++ni)
        acc[mi][ni] = (f32x4){0.f,0.f,0.f,0.f};

    // stage one 32-wide K-slice of A and B into buffer buf (linear LDS dest,
    // inverse-swizzled global source; 4 global_load_lds per thread)
    auto stage = [&](int k0, int buf) {
      #pragma unroll
      for (int call = 0; call < 2; ++call) {
        int p   = (call*4 + wave)*64 + lane;
        int row = p >> 2;
        int sl  = (p & 3) ^ (row & 3);
        const bf16_t* ga = vb + (size_t)(R0   + row)*KD + k0 + sl*8;
        const bf16_t* gb = ab + (size_t)(tcol + row)*KD + k0 + sl*8;
        char* la = lds + buf*16384 +        (call*4 + wave)*1024;
        char* lb = lds + buf*16384 + 8192 + (call*4 + wave)*1024;
        load_lds16(ga, la);
        load_lds16(gb, lb);
      }
    };

    // ---- pipelined K-loop: depth-2 prefetch, counted vmcnt ----
    // Safety: stage(s+2) targets buf[(s-1)%3], whose ds_reads finished
    // before barrier#2 of step s-1 (LGKM0+SBAR), which precedes this issue.
    stage(0, 0);
    stage(32, 1);
    #pragma unroll
    for (int s = 0; s < 16; ++s) {
      if (s <= 13) stage((s+2)*32, (s+2)%3);
      if (s <= 13)      VMW8();              // own stage(s) loads landed
      else if (s == 14) VMW4();
      else              VMW0();
      SBAR(); SCHED0();                      // whole buffer visible
      const char* Ab = lds + (s%3)*16384;
      const char* Bb = Ab + 8192;
      int ko = ((q ^ (r & 3)) << 4);
      bf16x8 af[4], bfr[4];
      #pragma unroll
      for (int mi = 0; mi < 4; ++mi)
        af[mi] = *(const bf16x8*)(Ab + (wr*64 + mi*16 + r)*64 + ko);
      #pragma unroll
      for (int ni = 0; ni < 4; ++ni)
        bfr[ni] = *(const bf16x8*)(Bb + (wc*64 + ni*16 + r)*64 + ko);
      LGKM0();
      SBAR(); SCHED0();                      // reads done -> buf reusable
      __builtin_amdgcn_s_setprio(1);
      #pragma unroll
      for (int mi = 0; mi < 4; ++mi)
        #pragma unroll
        for (int ni = 0; ni < 4; ++ni)
          acc[mi][ni] = __builtin_amdgcn_mfma_f32_16x16x32_bf16(af[mi], bfr[ni], acc[mi][ni], 0, 0, 0);
      __builtin_amdgcn_s_setprio(0);
    }

    // ---- diag mask once, in registers ----
    if (tcol == R0 && wr == wc && (r >> 2) == q) {
      #pragma unroll
      for (int mi = 0; mi < 4; ++mi)
        acc[mi][mi][r & 3] = NEG_INF;
    }

    // ---- column top5 (a2v): per-thread reduce, LDS merge, global write ----
    {
      float c5[4][5];
      #pragma unroll
      for (int ni = 0; ni < 4; ++ni) {
        #pragma unroll
        for (int z = 0; z < 5; ++z) c5[ni][z] = NEG_INF;
        #pragma unroll
        for (int mi = 0; mi < 4; ++mi)
          #pragma unroll
          for (int rg = 0; rg < 4; ++rg)
            TRY5(acc[mi][ni][rg], c5[ni][0],c5[ni][1],c5[ni][2],c5[ni][3],c5[ni][4]);
      }
      float* cm = (float*)lds;               // [128][8][5] = 20KB (aliases bufs)
      int cp2 = wr*4 + q;
      #pragma unroll
      for (int ni = 0; ni < 4; ++ni) {
        int cl = wc*64 + ni*16 + r;
        float* d = cm + ((size_t)cl*8 + cp2)*5;
        #pragma unroll
        for (int z = 0; z < 5; ++z) d[z] = c5[ni][z];
      }
      __syncthreads();
      if (tid < 128) {
        const float* s = cm + (size_t)tid*40;
        float m0=NEG_INF,m1=NEG_INF,m2=NEG_INF,m3=NEG_INF,m4=NEG_INF;
        #pragma unroll
        for (int j = 0; j < 40; ++j) TRY5(s[j], m0,m1,m2,m3,m4);
        float* dst = t5a + ((size_t)(tcol + tid)*64 + panel)*5;
        dst[0]=m0; dst[1]=m1; dst[2]=m2; dst[3]=m3; dst[4]=m4;
      }
      __syncthreads();
    }

    // ---- row top5 (v2a): C-halves through 32KB swizzled LDS tile ----
#define WRITE_FRAGS do { \
    _Pragma("unroll") \
    for (int mi_ = 0; mi_ < 4; ++mi_) { \
      _Pragma("unroll") \
      for (int ni_ = 0; ni_ < 4; ++ni_) { \
        int col_ = wc*64 + ni_*16 + r; \
        _Pragma("unroll") \
        for (int rg_ = 0; rg_ < 4; ++rg_) { \
          int rl_ = mi_*16 + q*4 + rg_; \
          int byte_ = ((rl_*128 + col_) << 2) ^ ((rl_ & 7) << 4); \
          *(float*)(lds + byte_) = acc[mi_][ni_][rg_]; \
        } \
      } \
    } } while(0)

#define SCAN_HALF(A0,A1,A2,A3,A4) do { \
    int rl_ = tid & 63; int cp_ = tid >> 6; \
    _Pragma("unroll") \
    for (int j_ = 0; j_ < 8; ++j_) { \
      int cs_ = cp_*8 + j_; \
      f32x4 vv = *(const f32x4*)(lds + rl_*512 + ((cs_ ^ (rl_ & 7)) << 4)); \
      float mx_ = fmaxf(fmaxf(vv[0],vv[1]), fmaxf(vv[2],vv[3])); \
      if (mx_ > A4) { \
        TRY5(vv[0], A0,A1,A2,A3,A4); \
        TRY5(vv[1], A0,A1,A2,A3,A4); \
        TRY5(vv[2], A0,A1,A2,A3,A4); \
        TRY5(vv[3], A0,A1,A2,A3,A4); \
      } \
    } } while(0)

    if (wr == 0) WRITE_FRAGS;
    __syncthreads();
    SCAN_HALF(sA0,sA1,sA2,sA3,sA4);
    __syncthreads();
    if (wr == 1) WRITE_FRAGS;
    __syncthreads();
    SCAN_HALF(sB0,sB1,sB2,sB3,sB4);
    __syncthreads();
    VMW0();   // drain t5a store acks: exact vmcnt counts for next tile
  }

  // ---- merge 4 col-subset copies per row, write chunk top5 ----
  float* t5m = (float*)lds;                   // [128][4][5]
  {
    int rl = tid & 63, cp = tid >> 6;
    float* d0 = t5m + ((size_t)rl*4 + cp)*5;
    d0[0]=sA0; d0[1]=sA1; d0[2]=sA2; d0[3]=sA3; d0[4]=sA4;
    float* d1 = t5m + ((size_t)(64 + rl)*4 + cp)*5;
    d1[0]=sB0; d1[1]=sB1; d1[2]=sB2; d1[3]=sB3; d1[4]=sB4;
  }
  __syncthreads();
  if (tid < 128) {
    int h = tid >> 6, rr = tid & 63;
    const float* s = t5m + ((size_t)(h*64 + rr)*4)*5;
    float m0=NEG_INF,m1=NEG_INF,m2=NEG_INF,m3=NEG_INF,m4=NEG_INF;
    #pragma unroll
    for (int j = 0; j < 20; ++j) TRY5(s[j], m0,m1,m2,m3,m4);
    int grow = R0 + h*64 + rr;
    float* dst = t5v + ((size_t)grow*16 + chunk)*5;
    dst[0]=m0; dst[1]=m1; dst[2]=m2; dst[3]=m3; dst[4]=m4;
  }
}

// ---------------- kernel 3: per-row merge + logsumexp ----------------------
__global__ __launch_bounds__(128)
void merge_kernel(const float* __restrict__ t5v, const float* __restrict__ t5a,
                  const float* __restrict__ pos, float* __restrict__ partials)
{
  int i = blockIdx.x*128 + threadIdx.x;
  float p = pos[i];
  float total = 0.f;
  {
    const float* s = t5v + (size_t)i*16*5;
    float a0=NEG_INF,a1=NEG_INF,a2=NEG_INF,a3=NEG_INF,a4=NEG_INF;
    for (int j = 0; j < 80; ++j) TRY5(s[j], a0,a1,a2,a3,a4);
    float m = fmaxf(p, a0*TSCALE);
    float sum = expf(p - m)
              + expf(a0*TSCALE - m) + expf(a1*TSCALE - m) + expf(a2*TSCALE - m)
              + expf(a3*TSCALE - m) + expf(a4*TSCALE - m);
    total += m + logf(sum) - p;
  }
  {
    const float* s = t5a + (size_t)i*64*5;
    float a0=NEG_INF,a1=NEG_INF,a2=NEG_INF,a3=NEG_INF,a4=NEG_INF;
    for (int j = 0; j < 320; ++j) TRY5(s[j], a0,a1,a2,a3,a4);
    float m = fmaxf(p, a0*TSCALE);
    float sum = expf(p - m)
              + expf(a0*TSCALE - m) + expf(a1*TSCALE - m) + expf(a2*TSCALE - m)
              + expf(a3*TSCALE - m) + expf(a4*TSCALE - m);
    total += m + logf(sum) - p;
  }
  #pragma unroll
  for (int m = 32; m; m >>= 1) total += __shfl_xor(total, m);
  __shared__ float wsum[2];
  if ((threadIdx.x & 63) == 0) wsum[threadIdx.x >> 6] = total;
  __syncthreads();
  if (threadIdx.x == 0) partials[blockIdx.x] = wsum[0] + wsum[1];
}

// ---------------- kernel 4: final scalar -----------------------------------
__global__ void final_kernel(const float* __restrict__ partials, float* __restrict__ out)
{
  int lane = threadIdx.x;
  float v = partials[lane];
  #pragma unroll
  for (int m = 32; m; m >>= 1) v += __shfl_xor(v, m);
  if (lane == 0) out[0] = 0.5f * v / 8192.0f;
}

// ---------------------------------------------------------------------------
extern "C" void kernel_launch(void* const* d_in, const int* in_sizes, int n_in,
                              void* d_out, int out_size, void* d_ws, size_t ws_size,
                              hipStream_t stream)
{
  const float* v = (const float*)d_in[0];
  const float* a = (const float*)d_in[1];
  char* ws = (char*)d_ws;

  constexpr size_t OFF_AB   = 8ull*1024*1024;
  constexpr size_t OFF_POS  = 16ull*1024*1024;
  constexpr size_t OFF_T5V  = OFF_POS + 64*1024;
  constexpr size_t OFF_T5A  = OFF_T5V + 3ull*1024*1024;   // t5v = 2.56MB
  constexpr size_t T5A_B    = 8192ull*64*5*4;             // 10MB
  constexpr size_t OFF_PART = OFF_T5A + T5A_B + 1024;

  bf16_t* vb  = (bf16_t*)ws;
  bf16_t* ab  = (bf16_t*)(ws + OFF_AB);
  float* pos  = (float*)(ws + OFF_POS);
  float* t5v  = (float*)(ws + OFF_T5V);
  float* t5a  = (float*)(ws + OFF_T5A);
  float* part = (float*)(ws + OFF_PART);
  float* out  = (float*)d_out;

  hipLaunchKernelGGL(nrm_kernel,   dim3(2048), dim3(256), 0, stream, v, a, vb, ab, pos);
  hipLaunchKernelGGL(gemm_topk,    dim3(1024), dim3(256), 0, stream, vb, ab, t5v, t5a);
  hipLaunchKernelGGL(merge_kernel, dim3(64),   dim3(128), 0, stream, t5v, t5a, pos, part);
  hipLaunchKernelGGL(final_kernel, dim3(1),    dim3(64),  0, stream, part, out);
}

// Round 4
// 308.139 us; speedup vs baseline: 2.2359x; 2.1136x over previous
//
#include <hip/hip_runtime.h>
#include <cstdint>
#include <cstddef>

// ---------------------------------------------------------------------------
// HardInfoNCESyncLoss (B=8192, D=512) — round 4: DECOUPLED pipeline.
//   nrm -> gemm_sim (materialize sim bf16, m97-structure GEMM) ->
//   rowscan (top5 per row) -> colscan (top5 per col) -> merge -> final
// Purpose: localize the ~470us fixed cost the fused kernels carried.
// ---------------------------------------------------------------------------

#define TSCALE (1.0f/0.07f)
#define NEG_INF (-__builtin_inff())
#define KD 512
#define NB 8192

typedef __bf16 bf16_t;
typedef __bf16 bf16x8 __attribute__((ext_vector_type(8)));
typedef float  f32x4  __attribute__((ext_vector_type(4)));
typedef unsigned short ushort_t;
typedef unsigned short ushort8 __attribute__((ext_vector_type(8)));

#define TRY5(v, A0,A1,A2,A3,A4) do { float _v=(v); \
  if (_v > A4) { \
    if (_v > A2) { \
      if (_v > A0)      { A4=A3; A3=A2; A2=A1; A1=A0; A0=_v; } \
      else if (_v > A1) { A4=A3; A3=A2; A2=A1; A1=_v; } \
      else              { A4=A3; A3=A2; A2=_v; } \
    } else { \
      if (_v > A3)      { A4=A3; A3=_v; } \
      else              { A4=_v; } \
    } \
  } } while(0)

static __device__ __forceinline__ void load_lds16(const void* g, void* l) {
  __builtin_amdgcn_global_load_lds(
      (const __attribute__((address_space(1))) void*)g,
      (__attribute__((address_space(3))) void*)(uint32_t)(uintptr_t)l,
      16, 0, 0);
}

static __device__ __forceinline__ float b2f(ushort_t u) {
  union { uint32_t i; float f; } x; x.i = ((uint32_t)u) << 16; return x.f;
}

// ---------------- kernel 1: L2-normalize, bf16 convert, exact pos ----------
__global__ __launch_bounds__(256)
void nrm_kernel(const float* __restrict__ v, const float* __restrict__ a,
                bf16_t* __restrict__ vb, bf16_t* __restrict__ ab,
                float* __restrict__ pos)
{
  int row  = blockIdx.x * 4 + (threadIdx.x >> 6);
  int lane = threadIdx.x & 63;
  size_t base = (size_t)row * 512 + (size_t)lane * 8;
  float4 v0 = *(const float4*)(v + base);
  float4 v1 = *(const float4*)(v + base + 4);
  float4 a0 = *(const float4*)(a + base);
  float4 a1 = *(const float4*)(a + base + 4);

  float sv = v0.x*v0.x+v0.y*v0.y+v0.z*v0.z+v0.w*v0.w
           + v1.x*v1.x+v1.y*v1.y+v1.z*v1.z+v1.w*v1.w;
  float sa = a0.x*a0.x+a0.y*a0.y+a0.z*a0.z+a0.w*a0.w
           + a1.x*a1.x+a1.y*a1.y+a1.z*a1.z+a1.w*a1.w;
  float sd = v0.x*a0.x+v0.y*a0.y+v0.z*a0.z+v0.w*a0.w
           + v1.x*a1.x+v1.y*a1.y+v1.z*a1.z+v1.w*a1.w;
  #pragma unroll
  for (int m = 32; m; m >>= 1) {
    sv += __shfl_xor(sv, m);
    sa += __shfl_xor(sa, m);
    sd += __shfl_xor(sd, m);
  }
  float iv = 1.0f / fmaxf(sqrtf(sv), 1e-12f);
  float ia = 1.0f / fmaxf(sqrtf(sa), 1e-12f);

  bf16x8 ov, oa;
  ov[0]=(bf16_t)(v0.x*iv); ov[1]=(bf16_t)(v0.y*iv); ov[2]=(bf16_t)(v0.z*iv); ov[3]=(bf16_t)(v0.w*iv);
  ov[4]=(bf16_t)(v1.x*iv); ov[5]=(bf16_t)(v1.y*iv); ov[6]=(bf16_t)(v1.z*iv); ov[7]=(bf16_t)(v1.w*iv);
  oa[0]=(bf16_t)(a0.x*ia); oa[1]=(bf16_t)(a0.y*ia); oa[2]=(bf16_t)(a0.z*ia); oa[3]=(bf16_t)(a0.w*ia);
  oa[4]=(bf16_t)(a1.x*ia); oa[5]=(bf16_t)(a1.y*ia); oa[6]=(bf16_t)(a1.z*ia); oa[7]=(bf16_t)(a1.w*ia);
  *(bf16x8*)(vb + base) = ov;
  *(bf16x8*)(ab + base) = oa;
  if (lane == 0) pos[row] = sd * iv * ia * TSCALE;
}

// ---------------- kernel 2: pure GEMM, sim = vb x ab^T as bf16 -------------
// m97 structure: 128^2 tile, BK=32, double-buffered LDS (32KB), one
// __syncthreads per K-step. 4096 blocks, XCD-swizzled.
__global__ __launch_bounds__(256, 4)
void gemm_sim(const bf16_t* __restrict__ vb, const bf16_t* __restrict__ ab,
              bf16_t* __restrict__ sim)
{
  __shared__ __align__(16) char lds[32768];   // buf0 @0 (A8K,B8K), buf1 @16K
  int tid  = threadIdx.x;
  int wave = tid >> 6;
  int lane = tid & 63;
  int wr = wave >> 1, wc = wave & 1;
  int r = lane & 15, q = lane >> 4;

  int wg = (blockIdx.x & 7) * 512 + (blockIdx.x >> 3);   // XCD-contig
  int tr = wg >> 6, tc = wg & 63;
  int R0 = tr << 7, C0 = tc << 7;

  f32x4 acc[4][4];
  #pragma unroll
  for (int mi = 0; mi < 4; ++mi)
    #pragma unroll
    for (int ni = 0; ni < 4; ++ni)
      acc[mi][ni] = (f32x4){0.f,0.f,0.f,0.f};

  auto stage = [&](int k0, int buf) {
    #pragma unroll
    for (int call = 0; call < 2; ++call) {
      int p   = (call*4 + wave)*64 + lane;
      int row = p >> 2;
      int sl  = (p & 3) ^ (row & 3);           // involution swizzle on source
      const bf16_t* ga = vb + (size_t)(R0 + row)*KD + k0 + sl*8;
      const bf16_t* gb = ab + (size_t)(C0 + row)*KD + k0 + sl*8;
      char* la = lds + buf*16384 +        (call*4 + wave)*1024;  // wave-uniform
      char* lb = lds + buf*16384 + 8192 + (call*4 + wave)*1024;
      load_lds16(ga, la);
      load_lds16(gb, lb);
    }
  };

  stage(0, 0);
  __syncthreads();
  #pragma unroll
  for (int ks = 0; ks < 16; ++ks) {            // K = 512
    int cur = ks & 1;
    if (ks < 15) stage((ks+1)*32, cur ^ 1);
    const char* Ab = lds + cur*16384;
    const char* Bb = Ab + 8192;
    int ko = ((q ^ (r & 3)) << 4);
    bf16x8 af[4], bfr[4];
    #pragma unroll
    for (int mi = 0; mi < 4; ++mi)
      af[mi] = *(const bf16x8*)(Ab + (wr*64 + mi*16 + r)*64 + ko);
    #pragma unroll
    for (int ni = 0; ni < 4; ++ni)
      bfr[ni] = *(const bf16x8*)(Bb + (wc*64 + ni*16 + r)*64 + ko);
    #pragma unroll
    for (int mi = 0; mi < 4; ++mi)
      #pragma unroll
      for (int ni = 0; ni < 4; ++ni)
        acc[mi][ni] = __builtin_amdgcn_mfma_f32_16x16x32_bf16(af[mi], bfr[ni], acc[mi][ni], 0, 0, 0);
    __syncthreads();                            // stage(ks+1) landed; reads done
  }

  // epilogue: two 64-row halves through swizzled fp32 LDS tile -> bf16 stores
  #pragma unroll
  for (int h = 0; h < 2; ++h) {
    if (wr == h) {
      #pragma unroll
      for (int mi = 0; mi < 4; ++mi)
        #pragma unroll
        for (int ni = 0; ni < 4; ++ni) {
          int col = wc*64 + ni*16 + r;
          #pragma unroll
          for (int rg = 0; rg < 4; ++rg) {
            int rl = mi*16 + q*4 + rg;
            int byte = ((rl*128 + col) << 2) ^ ((rl & 7) << 4);
            *(float*)(lds + byte) = acc[mi][ni][rg];
          }
        }
    }
    __syncthreads();
    {
      int rl = tid & 63, cp = tid >> 6;
      size_t gbase = (size_t)(R0 + h*64 + rl)*NB + C0 + cp*32;
      #pragma unroll
      for (int j2 = 0; j2 < 4; ++j2) {
        int cs0 = cp*8 + j2*2;
        f32x4 v0 = *(const f32x4*)(lds + rl*512 + ((cs0     ^ (rl & 7)) << 4));
        f32x4 v1 = *(const f32x4*)(lds + rl*512 + (((cs0+1) ^ (rl & 7)) << 4));
        bf16x8 o;
        o[0]=(bf16_t)v0[0]; o[1]=(bf16_t)v0[1]; o[2]=(bf16_t)v0[2]; o[3]=(bf16_t)v0[3];
        o[4]=(bf16_t)v1[0]; o[5]=(bf16_t)v1[1]; o[6]=(bf16_t)v1[2]; o[7]=(bf16_t)v1[3];
        *(bf16x8*)(sim + gbase + j2*8) = o;
      }
    }
    __syncthreads();
  }
}

// ---------------- kernel 3: row top5 (v2a) ---------------------------------
// 2048 blocks x 4 waves; wave w scans row blockIdx.x*4+w (16KB, coalesced).
__global__ __launch_bounds__(256)
void rowscan(const bf16_t* __restrict__ sim, float* __restrict__ t5v)
{
  int row  = blockIdx.x * 4 + (threadIdx.x >> 6);
  int lane = threadIdx.x & 63;
  const ushort_t* rp = (const ushort_t*)(sim + (size_t)row * NB);

  float a0=NEG_INF,a1=NEG_INF,a2=NEG_INF,a3=NEG_INF,a4=NEG_INF;
  #pragma unroll
  for (int it = 0; it < 16; ++it) {
    int col0 = it*512 + lane*8;
    ushort8 u = *(const ushort8*)(rp + col0);
    float f[8];
    #pragma unroll
    for (int j = 0; j < 8; ++j) f[j] = b2f(u[j]);
    if ((col0 >> 3) == (row >> 3)) f[row & 7] = NEG_INF;   // diagonal
    float mx = fmaxf(fmaxf(fmaxf(f[0],f[1]),fmaxf(f[2],f[3])),
                     fmaxf(fmaxf(f[4],f[5]),fmaxf(f[6],f[7])));
    if (mx > a4) {
      #pragma unroll
      for (int j = 0; j < 8; ++j) TRY5(f[j], a0,a1,a2,a3,a4);
    }
  }
  // butterfly merge of sorted-5 lists across 64 lanes
  #pragma unroll
  for (int m = 1; m < 64; m <<= 1) {
    float b0=__shfl_xor(a0,m), b1=__shfl_xor(a1,m), b2=__shfl_xor(a2,m),
          b3=__shfl_xor(a3,m), b4=__shfl_xor(a4,m);
    TRY5(b0, a0,a1,a2,a3,a4); TRY5(b1, a0,a1,a2,a3,a4);
    TRY5(b2, a0,a1,a2,a3,a4); TRY5(b3, a0,a1,a2,a3,a4);
    TRY5(b4, a0,a1,a2,a3,a4);
  }
  if (lane == 0) {
    float* d = t5v + (size_t)row*5;
    d[0]=a0; d[1]=a1; d[2]=a2; d[3]=a3; d[4]=a4;
  }
}

// ---------------- kernel 4: col top5 (a2v), partials -----------------------
// 1024 blocks = 64 col-panels x 16 row-sixteenths. Per chunk: stage 128x128
// bf16 tile into XOR-swizzled LDS (coalesced global reads), scan columns.
__global__ __launch_bounds__(256)
void colscan(const bf16_t* __restrict__ sim, float* __restrict__ t5a)
{
  __shared__ __align__(16) char tile[32768];   // [128 rows][16 granules x 16B]
  int tid   = threadIdx.x;
  int panel = blockIdx.x >> 4;
  int six   = blockIdx.x & 15;
  int C0 = panel << 7;
  int Rb = six << 9;                           // 512 rows per block

  int col = tid & 127, h = tid >> 7;           // scan role
  int lrow = tid >> 1, gp = (tid & 1) * 8;     // load role

  float a0=NEG_INF,a1=NEG_INF,a2=NEG_INF,a3=NEG_INF,a4=NEG_INF;

  for (int ch = 0; ch < 4; ++ch) {
    int R = Rb + ch*128;
    __syncthreads();                           // protect tile from prev reads
    #pragma unroll
    for (int i = 0; i < 8; ++i) {
      int g = gp + i;
      bf16x8 x = *(const bf16x8*)(sim + (size_t)(R + lrow)*NB + C0 + g*8);
      *(bf16x8*)(tile + lrow*256 + ((g ^ (lrow & 7)) << 4)) = x;
    }
    __syncthreads();
    int diag = C0 + col - R;                   // row index that equals col
    #pragma unroll 8
    for (int rr = 0; rr < 64; ++rr) {
      int row = h*64 + rr;
      ushort_t u = *(const ushort_t*)(tile + row*256 +
                     (((col >> 3) ^ (row & 7)) << 4) + (col & 7)*2);
      float f = b2f(u);
      if (row == diag) f = NEG_INF;
      TRY5(f, a0,a1,a2,a3,a4);
    }
  }

  // merge h=0/1 pairs
  float* m = (float*)tile;                     // [128][2][5]
  __syncthreads();
  {
    float* d = m + ((size_t)col*2 + h)*5;
    d[0]=a0; d[1]=a1; d[2]=a2; d[3]=a3; d[4]=a4;
  }
  __syncthreads();
  if (tid < 128) {
    const float* s = m + (size_t)tid*10;
    float m0=NEG_INF,m1=NEG_INF,m2=NEG_INF,m3=NEG_INF,m4=NEG_INF;
    #pragma unroll
    for (int j = 0; j < 10; ++j) TRY5(s[j], m0,m1,m2,m3,m4);
    float* dst = t5a + ((size_t)(C0 + tid)*16 + six)*5;
    dst[0]=m0; dst[1]=m1; dst[2]=m2; dst[3]=m3; dst[4]=m4;
  }
}

// ---------------- kernel 5: per-row merge + logsumexp ----------------------
__global__ __launch_bounds__(128)
void merge_kernel(const float* __restrict__ t5v, const float* __restrict__ t5a,
                  const float* __restrict__ pos, float* __restrict__ partials)
{
  int i = blockIdx.x*128 + threadIdx.x;
  float p = pos[i];                            // pre-scaled by 1/T
  float total = 0.f;
  {
    const float* s = t5v + (size_t)i*5;        // already final row top5
    float m = fmaxf(p, s[0]*TSCALE);
    float sum = expf(p - m)
              + expf(s[0]*TSCALE - m) + expf(s[1]*TSCALE - m) + expf(s[2]*TSCALE - m)
              + expf(s[3]*TSCALE - m) + expf(s[4]*TSCALE - m);
    total += m + logf(sum) - p;
  }
  {
    const float* s = t5a + (size_t)i*16*5;
    float a0=NEG_INF,a1=NEG_INF,a2=NEG_INF,a3=NEG_INF,a4=NEG_INF;
    for (int j = 0; j < 80; ++j) TRY5(s[j], a0,a1,a2,a3,a4);
    float m = fmaxf(p, a0*TSCALE);
    float sum = expf(p - m)
              + expf(a0*TSCALE - m) + expf(a1*TSCALE - m) + expf(a2*TSCALE - m)
              + expf(a3*TSCALE - m) + expf(a4*TSCALE - m);
    total += m + logf(sum) - p;
  }
  #pragma unroll
  for (int m = 32; m; m >>= 1) total += __shfl_xor(total, m);
  __shared__ float wsum[2];
  if ((threadIdx.x & 63) == 0) wsum[threadIdx.x >> 6] = total;
  __syncthreads();
  if (threadIdx.x == 0) partials[blockIdx.x] = wsum[0] + wsum[1];
}

// ---------------- kernel 6: final scalar -----------------------------------
__global__ void final_kernel(const float* __restrict__ partials, float* __restrict__ out)
{
  int lane = threadIdx.x;
  float v = partials[lane];
  #pragma unroll
  for (int m = 32; m; m >>= 1) v += __shfl_xor(v, m);
  if (lane == 0) out[0] = 0.5f * v / 8192.0f;
}

// ---------------------------------------------------------------------------
extern "C" void kernel_launch(void* const* d_in, const int* in_sizes, int n_in,
                              void* d_out, int out_size, void* d_ws, size_t ws_size,
                              hipStream_t stream)
{
  const float* v = (const float*)d_in[0];
  const float* a = (const float*)d_in[1];
  char* ws = (char*)d_ws;

  constexpr size_t OFF_AB   = 8ull*1024*1024;
  constexpr size_t OFF_POS  = 16ull*1024*1024;
  constexpr size_t OFF_T5V  = OFF_POS + 64*1024;          // 160KB
  constexpr size_t OFF_T5A  = OFF_T5V + 256*1024;         // 2.56MB
  constexpr size_t OFF_PART = OFF_T5A + 3ull*1024*1024;
  constexpr size_t OFF_SIM  = 24ull*1024*1024;            // 128MB bf16 sim

  bf16_t* vb  = (bf16_t*)ws;
  bf16_t* ab  = (bf16_t*)(ws + OFF_AB);
  float* pos  = (float*)(ws + OFF_POS);
  float* t5v  = (float*)(ws + OFF_T5V);
  float* t5a  = (float*)(ws + OFF_T5A);
  float* part = (float*)(ws + OFF_PART);
  bf16_t* sim = (bf16_t*)(ws + OFF_SIM);
  float* out  = (float*)d_out;

  hipLaunchKernelGGL(nrm_kernel,   dim3(2048), dim3(256), 0, stream, v, a, vb, ab, pos);
  hipLaunchKernelGGL(gemm_sim,     dim3(4096), dim3(256), 0, stream, vb, ab, sim);
  hipLaunchKernelGGL(rowscan,      dim3(2048), dim3(256), 0, stream, sim, t5v);
  hipLaunchKernelGGL(colscan,      dim3(1024), dim3(256), 0, stream, sim, t5a);
  hipLaunchKernelGGL(merge_kernel, dim3(64),   dim3(128), 0, stream, t5v, t5a, pos, part);
  hipLaunchKernelGGL(final_kernel, dim3(1),    dim3(64),  0, stream, part, out);
}

// Round 5
// 233.733 us; speedup vs baseline: 2.9477x; 1.3183x over previous
//
#include <hip/hip_runtime.h>
#include <cstdint>
#include <cstddef>

// ---------------------------------------------------------------------------
// HardInfoNCESyncLoss (B=8192, D=512) — round 5.
// R4 showed: m97-structure GEMM with 4096 one-tile blocks = 124us; the
// sim materialization (write 128MB + re-read 256MB) cost ~180us. This round
// fuses row/col top5 into the GEMM epilogue per tile (R2's proven epilogue,
// R4's proven grid), writing only 5-float partials (2 x 10.5MB).
//   nrm -> gemm_topk (fused) -> merge (wave/row butterfly) -> final
// ---------------------------------------------------------------------------

#define TSCALE (1.0f/0.07f)
#define NEG_INF (-__builtin_inff())
#define KD 512
#define NB 8192

typedef __bf16 bf16_t;
typedef __bf16 bf16x8 __attribute__((ext_vector_type(8)));
typedef float  f32x4  __attribute__((ext_vector_type(4)));

#define TRY5(v, A0,A1,A2,A3,A4) do { float _v=(v); \
  if (_v > A4) { \
    if (_v > A2) { \
      if (_v > A0)      { A4=A3; A3=A2; A2=A1; A1=A0; A0=_v; } \
      else if (_v > A1) { A4=A3; A3=A2; A2=A1; A1=_v; } \
      else              { A4=A3; A3=A2; A2=_v; } \
    } else { \
      if (_v > A3)      { A4=A3; A3=_v; } \
      else              { A4=_v; } \
    } \
  } } while(0)

static __device__ __forceinline__ void load_lds16(const void* g, void* l) {
  __builtin_amdgcn_global_load_lds(
      (const __attribute__((address_space(1))) void*)g,
      (__attribute__((address_space(3))) void*)(uint32_t)(uintptr_t)l,
      16, 0, 0);
}

// ---------------- kernel 1: L2-normalize, bf16 convert, exact pos ----------
__global__ __launch_bounds__(256)
void nrm_kernel(const float* __restrict__ v, const float* __restrict__ a,
                bf16_t* __restrict__ vb, bf16_t* __restrict__ ab,
                float* __restrict__ pos)
{
  int row  = blockIdx.x * 4 + (threadIdx.x >> 6);
  int lane = threadIdx.x & 63;
  size_t base = (size_t)row * 512 + (size_t)lane * 8;
  float4 v0 = *(const float4*)(v + base);
  float4 v1 = *(const float4*)(v + base + 4);
  float4 a0 = *(const float4*)(a + base);
  float4 a1 = *(const float4*)(a + base + 4);

  float sv = v0.x*v0.x+v0.y*v0.y+v0.z*v0.z+v0.w*v0.w
           + v1.x*v1.x+v1.y*v1.y+v1.z*v1.z+v1.w*v1.w;
  float sa = a0.x*a0.x+a0.y*a0.y+a0.z*a0.z+a0.w*a0.w
           + a1.x*a1.x+a1.y*a1.y+a1.z*a1.z+a1.w*a1.w;
  float sd = v0.x*a0.x+v0.y*a0.y+v0.z*a0.z+v0.w*a0.w
           + v1.x*a1.x+v1.y*a1.y+v1.z*a1.z+v1.w*a1.w;
  #pragma unroll
  for (int m = 32; m; m >>= 1) {
    sv += __shfl_xor(sv, m);
    sa += __shfl_xor(sa, m);
    sd += __shfl_xor(sd, m);
  }
  float iv = 1.0f / fmaxf(sqrtf(sv), 1e-12f);
  float ia = 1.0f / fmaxf(sqrtf(sa), 1e-12f);

  bf16x8 ov, oa;
  ov[0]=(bf16_t)(v0.x*iv); ov[1]=(bf16_t)(v0.y*iv); ov[2]=(bf16_t)(v0.z*iv); ov[3]=(bf16_t)(v0.w*iv);
  ov[4]=(bf16_t)(v1.x*iv); ov[5]=(bf16_t)(v1.y*iv); ov[6]=(bf16_t)(v1.z*iv); ov[7]=(bf16_t)(v1.w*iv);
  oa[0]=(bf16_t)(a0.x*ia); oa[1]=(bf16_t)(a0.y*ia); oa[2]=(bf16_t)(a0.z*ia); oa[3]=(bf16_t)(a0.w*ia);
  oa[4]=(bf16_t)(a1.x*ia); oa[5]=(bf16_t)(a1.y*ia); oa[6]=(bf16_t)(a1.z*ia); oa[7]=(bf16_t)(a1.w*ia);
  *(bf16x8*)(vb + base) = ov;
  *(bf16x8*)(ab + base) = oa;
  if (lane == 0) pos[row] = sd * iv * ia * TSCALE;
}

// ---------------- kernel 2: GEMM tile + fused row/col top5 partials --------
// 4096 blocks (XCD-contig swizzle), each ONE 128x128 tile of sim.
// Row partials -> t5v[row][tc][5]; col partials -> t5a[col][tr][5].
__global__ __launch_bounds__(256, 4)
void gemm_topk(const bf16_t* __restrict__ vb, const bf16_t* __restrict__ ab,
               float* __restrict__ t5v, float* __restrict__ t5a)
{
  __shared__ __align__(16) char lds[32768];   // staging 2x16KB; epilogue reuse
  int tid  = threadIdx.x;
  int wave = tid >> 6;
  int lane = tid & 63;
  int wr = wave >> 1, wc = wave & 1;
  int r = lane & 15, q = lane >> 4;

  int wg = (blockIdx.x & 7) * 512 + (blockIdx.x >> 3);   // XCD-contig
  int tr = wg >> 6, tc = wg & 63;
  int R0 = tr << 7, C0 = tc << 7;

  f32x4 acc[4][4];
  #pragma unroll
  for (int mi = 0; mi < 4; ++mi)
    #pragma unroll
    for (int ni = 0; ni < 4; ++ni)
      acc[mi][ni] = (f32x4){0.f,0.f,0.f,0.f};

  auto stage = [&](int k0, int buf) {
    #pragma unroll
    for (int call = 0; call < 2; ++call) {
      int p   = (call*4 + wave)*64 + lane;
      int row = p >> 2;
      int sl  = (p & 3) ^ (row & 3);           // involution swizzle on source
      const bf16_t* ga = vb + (size_t)(R0 + row)*KD + k0 + sl*8;
      const bf16_t* gb = ab + (size_t)(C0 + row)*KD + k0 + sl*8;
      char* la = lds + buf*16384 +        (call*4 + wave)*1024;  // wave-uniform
      char* lb = lds + buf*16384 + 8192 + (call*4 + wave)*1024;
      load_lds16(ga, la);
      load_lds16(gb, lb);
    }
  };

  stage(0, 0);
  __syncthreads();
  #pragma unroll
  for (int ks = 0; ks < 16; ++ks) {            // K = 512
    int cur = ks & 1;
    if (ks < 15) stage((ks+1)*32, cur ^ 1);
    const char* Ab = lds + cur*16384;
    const char* Bb = Ab + 8192;
    int ko = ((q ^ (r & 3)) << 4);
    bf16x8 af[4], bfr[4];
    #pragma unroll
    for (int mi = 0; mi < 4; ++mi)
      af[mi] = *(const bf16x8*)(Ab + (wr*64 + mi*16 + r)*64 + ko);
    #pragma unroll
    for (int ni = 0; ni < 4; ++ni)
      bfr[ni] = *(const bf16x8*)(Bb + (wc*64 + ni*16 + r)*64 + ko);
    #pragma unroll
    for (int mi = 0; mi < 4; ++mi)
      #pragma unroll
      for (int ni = 0; ni < 4; ++ni)
        acc[mi][ni] = __builtin_amdgcn_mfma_f32_16x16x32_bf16(af[mi], bfr[ni], acc[mi][ni], 0, 0, 0);
    __syncthreads();                            // stage(ks+1) landed; reads done
  }

  // ---- diag mask once, in registers (serves both scans) ----
  // row = R0 + wr*64 + mi*16 + q*4 + rg ; col = C0 + wc*64 + ni*16 + r
  if (tr == tc && wr == wc && (r >> 2) == q) {
    #pragma unroll
    for (int mi = 0; mi < 4; ++mi)
      acc[mi][mi][r & 3] = NEG_INF;
  }

  // ---- col top5 partials (a2v): per-thread reduce over 16 rows, LDS merge --
  {
    float c5[4][5];
    #pragma unroll
    for (int ni = 0; ni < 4; ++ni) {
      #pragma unroll
      for (int z = 0; z < 5; ++z) c5[ni][z] = NEG_INF;
      #pragma unroll
      for (int mi = 0; mi < 4; ++mi)
        #pragma unroll
        for (int rg = 0; rg < 4; ++rg)
          TRY5(acc[mi][ni][rg], c5[ni][0],c5[ni][1],c5[ni][2],c5[ni][3],c5[ni][4]);
    }
    float* cm = (float*)lds;                 // [128 cols][8 copies][5] = 20KB
    int cp2 = wr*4 + q;
    #pragma unroll
    for (int ni = 0; ni < 4; ++ni) {
      int cl = wc*64 + ni*16 + r;
      float* d = cm + ((size_t)cl*8 + cp2)*5;
      #pragma unroll
      for (int z = 0; z < 5; ++z) d[z] = c5[ni][z];
    }
    __syncthreads();
    if (tid < 128) {
      const float* s = cm + (size_t)tid*40;
      float m0=NEG_INF,m1=NEG_INF,m2=NEG_INF,m3=NEG_INF,m4=NEG_INF;
      #pragma unroll
      for (int j = 0; j < 40; ++j) TRY5(s[j], m0,m1,m2,m3,m4);
      float* dst = t5a + ((size_t)(C0 + tid)*64 + tr)*5;
      dst[0]=m0; dst[1]=m1; dst[2]=m2; dst[3]=m3; dst[4]=m4;
    }
    __syncthreads();
  }

  // ---- row top5 partials (v2a): halves through 32KB swizzled LDS tile ----
  float sA0=NEG_INF,sA1=NEG_INF,sA2=NEG_INF,sA3=NEG_INF,sA4=NEG_INF;
  float sB0=NEG_INF,sB1=NEG_INF,sB2=NEG_INF,sB3=NEG_INF,sB4=NEG_INF;

#define WRITE_FRAGS do { \
    _Pragma("unroll") \
    for (int mi_ = 0; mi_ < 4; ++mi_) { \
      _Pragma("unroll") \
      for (int ni_ = 0; ni_ < 4; ++ni_) { \
        int col_ = wc*64 + ni_*16 + r; \
        _Pragma("unroll") \
        for (int rg_ = 0; rg_ < 4; ++rg_) { \
          int rl_ = mi_*16 + q*4 + rg_; \
          int byte_ = ((rl_*128 + col_) << 2) ^ ((rl_ & 7) << 4); \
          *(float*)(lds + byte_) = acc[mi_][ni_][rg_]; \
        } \
      } \
    } } while(0)

#define SCAN_HALF(A0,A1,A2,A3,A4) do { \
    int rl_ = tid & 63; int cp_ = tid >> 6; \
    _Pragma("unroll") \
    for (int j_ = 0; j_ < 8; ++j_) { \
      int cs_ = cp_*8 + j_; \
      f32x4 vv = *(const f32x4*)(lds + rl_*512 + ((cs_ ^ (rl_ & 7)) << 4)); \
      float mx_ = fmaxf(fmaxf(vv[0],vv[1]), fmaxf(vv[2],vv[3])); \
      if (mx_ > A4) { \
        TRY5(vv[0], A0,A1,A2,A3,A4); \
        TRY5(vv[1], A0,A1,A2,A3,A4); \
        TRY5(vv[2], A0,A1,A2,A3,A4); \
        TRY5(vv[3], A0,A1,A2,A3,A4); \
      } \
    } } while(0)

  if (wr == 0) WRITE_FRAGS;                   // rows 0..63
  __syncthreads();
  SCAN_HALF(sA0,sA1,sA2,sA3,sA4);
  __syncthreads();
  if (wr == 1) WRITE_FRAGS;                   // rows 64..127
  __syncthreads();
  SCAN_HALF(sB0,sB1,sB2,sB3,sB4);
  __syncthreads();

  // merge 4 col-subset copies per row, write tile row-top5
  float* t5m = (float*)lds;                   // [128][4][5] = 10KB
  {
    int rl = tid & 63, cp = tid >> 6;
    float* d0 = t5m + ((size_t)rl*4 + cp)*5;
    d0[0]=sA0; d0[1]=sA1; d0[2]=sA2; d0[3]=sA3; d0[4]=sA4;
    float* d1 = t5m + ((size_t)(64 + rl)*4 + cp)*5;
    d1[0]=sB0; d1[1]=sB1; d1[2]=sB2; d1[3]=sB3; d1[4]=sB4;
  }
  __syncthreads();
  if (tid < 128) {
    const float* s = t5m + (size_t)tid*20;
    float m0=NEG_INF,m1=NEG_INF,m2=NEG_INF,m3=NEG_INF,m4=NEG_INF;
    #pragma unroll
    for (int j = 0; j < 20; ++j) TRY5(s[j], m0,m1,m2,m3,m4);
    float* dst = t5v + ((size_t)(R0 + tid)*64 + tc)*5;
    dst[0]=m0; dst[1]=m1; dst[2]=m2; dst[3]=m3; dst[4]=m4;
  }
}

// ---------------- kernel 3: wave-per-row merge + logsumexp -----------------
// 2048 blocks x 4 waves. Lane l owns sorted group l (of 64); butterfly merge.
__global__ __launch_bounds__(256)
void merge_kernel(const float* __restrict__ t5v, const float* __restrict__ t5a,
                  const float* __restrict__ pos, float* __restrict__ rowloss)
{
  int row  = blockIdx.x * 4 + (threadIdx.x >> 6);
  int lane = threadIdx.x & 63;
  float p = pos[row];                          // pre-scaled by 1/T
  float total = 0.f;

  #pragma unroll
  for (int dir = 0; dir < 2; ++dir) {
    const float* s = (dir ? t5a : t5v) + ((size_t)row*64 + lane)*5;
    float a0=s[0], a1=s[1], a2=s[2], a3=s[3], a4=s[4];   // sorted desc
    #pragma unroll
    for (int m = 1; m < 64; m <<= 1) {
      float b0=__shfl_xor(a0,m), b1=__shfl_xor(a1,m), b2=__shfl_xor(a2,m),
            b3=__shfl_xor(a3,m), b4=__shfl_xor(a4,m);
      if (b0 > a4) {
        TRY5(b0, a0,a1,a2,a3,a4); TRY5(b1, a0,a1,a2,a3,a4);
        TRY5(b2, a0,a1,a2,a3,a4); TRY5(b3, a0,a1,a2,a3,a4);
        TRY5(b4, a0,a1,a2,a3,a4);
      }
    }
    float m = fmaxf(p, a0*TSCALE);
    float sum = expf(p - m)
              + expf(a0*TSCALE - m) + expf(a1*TSCALE - m) + expf(a2*TSCALE - m)
              + expf(a3*TSCALE - m) + expf(a4*TSCALE - m);
    total += m + logf(sum) - p;
  }
  if (lane == 0) rowloss[row] = total;
}

// ---------------- kernel 4: final scalar (sum 8192 rowlosses) --------------
__global__ __launch_bounds__(1024)
void final_kernel(const float* __restrict__ rowloss, float* __restrict__ out)
{
  int tid = threadIdx.x;
  float v = 0.f;
  #pragma unroll
  for (int j = 0; j < 8; ++j) v += rowloss[tid*8 + j];
  #pragma unroll
  for (int m = 32; m; m >>= 1) v += __shfl_xor(v, m);
  __shared__ float wsum[16];
  if ((tid & 63) == 0) wsum[tid >> 6] = v;
  __syncthreads();
  if (tid == 0) {
    float t = 0.f;
    #pragma unroll
    for (int j = 0; j < 16; ++j) t += wsum[j];
    out[0] = 0.5f * t / 8192.0f;
  }
}

// ---------------------------------------------------------------------------
extern "C" void kernel_launch(void* const* d_in, const int* in_sizes, int n_in,
                              void* d_out, int out_size, void* d_ws, size_t ws_size,
                              hipStream_t stream)
{
  const float* v = (const float*)d_in[0];
  const float* a = (const float*)d_in[1];
  char* ws = (char*)d_ws;

  constexpr size_t OFF_AB   = 8ull*1024*1024;
  constexpr size_t OFF_POS  = 16ull*1024*1024;
  constexpr size_t OFF_T5V  = 17ull*1024*1024;   // 8192*64*5*4 = 10.5MB
  constexpr size_t OFF_T5A  = 28ull*1024*1024;   // 10.5MB
  constexpr size_t OFF_RL   = 39ull*1024*1024;   // 32KB

  bf16_t* vb  = (bf16_t*)ws;
  bf16_t* ab  = (bf16_t*)(ws + OFF_AB);
  float* pos  = (float*)(ws + OFF_POS);
  float* t5v  = (float*)(ws + OFF_T5V);
  float* t5a  = (float*)(ws + OFF_T5A);
  float* rl   = (float*)(ws + OFF_RL);
  float* out  = (float*)d_out;

  hipLaunchKernelGGL(nrm_kernel,   dim3(2048), dim3(256), 0, stream, v, a, vb, ab, pos);
  hipLaunchKernelGGL(gemm_topk,    dim3(4096), dim3(256), 0, stream, vb, ab, t5v, t5a);
  hipLaunchKernelGGL(merge_kernel, dim3(2048), dim3(256), 0, stream, t5v, t5a, pos, rl);
  hipLaunchKernelGGL(final_kernel, dim3(1),    dim3(1024),0, stream, rl, out);
}